// Round 2
// baseline (483.763 us; speedup 1.0000x reference)
//
#include <hip/hip_runtime.h>
#include <math.h>

#define BB 16
#define SP1c 513
#define SS 512
#define VV 32000
#define NV4 (VV / 4)          // 8000 float4 per row
#define NROWS (BB * SS)       // 8192
#define THREADS 320           // 8000 / 320 = 25 iterations exactly

// ws layout: [0..8) u64 sum_ticks, [8..12) u32 count, [12..16) u32 done
struct WsAcc {
    unsigned long long sum_ticks;
    unsigned int count;
    unsigned int done;
};

#define UPD(M, S, v)                                                        \
    {                                                                       \
        float mx_ = fmaxf(fmaxf((v).x, (v).y), fmaxf((v).z, (v).w));        \
        float nm_ = fmaxf((M), mx_);                                        \
        (S) = (S) * __expf((M) - nm_) + __expf((v).x - nm_) +               \
              __expf((v).y - nm_) + __expf((v).z - nm_) +                   \
              __expf((v).w - nm_);                                          \
        (M) = nm_;                                                          \
    }

__global__ __launch_bounds__(THREADS) void ce_fused_kernel(
    const float* __restrict__ logits,   // (B, SP1, V) f32
    const int* __restrict__ trg,        // (B, SP1)
    const int* __restrict__ lengths,    // (B,)
    WsAcc* __restrict__ acc,            // zeroed by memsetAsync each launch
    float* __restrict__ out)            // scalar loss
{
    const int row = blockIdx.x;
    const int b = row >> 9;
    const int s = row & 511;

    const int tgt = trg[b * SP1c + (s + 1)];
    const bool valid = (s < lengths[b]) && (tgt != 0);

    if (valid) {
        const float* rowp = logits + ((size_t)b * SP1c + (s + 1)) * VV;
        const float4* rp4 = reinterpret_cast<const float4*>(rowp);

        // 5 independent online (max, sum-exp) accumulators: breaks the
        // serial exp-rescale chain; 5 loads in flight per round.
        float m0 = -1e30f, m1 = -1e30f, m2 = -1e30f, m3 = -1e30f, m4 = -1e30f;
        float s0 = 0.f, s1 = 0.f, s2 = 0.f, s3 = 0.f, s4 = 0.f;

        int i = threadIdx.x;
        #pragma unroll
        for (int r = 0; r < 5; ++r) {
            float4 v0 = rp4[i];
            float4 v1 = rp4[i + THREADS];
            float4 v2 = rp4[i + 2 * THREADS];
            float4 v3 = rp4[i + 3 * THREADS];
            float4 v4 = rp4[i + 4 * THREADS];
            UPD(m0, s0, v0)
            UPD(m1, s1, v1)
            UPD(m2, s2, v2)
            UPD(m3, s3, v3)
            UPD(m4, s4, v4)
            i += 5 * THREADS;
        }

        // Merge the 5 accumulators.
        float M = m0, Ssum = s0;
        {
            float nm = fmaxf(M, m1); Ssum = Ssum * __expf(M - nm) + s1 * __expf(m1 - nm); M = nm;
            nm = fmaxf(M, m2); Ssum = Ssum * __expf(M - nm) + s2 * __expf(m2 - nm); M = nm;
            nm = fmaxf(M, m3); Ssum = Ssum * __expf(M - nm) + s3 * __expf(m3 - nm); M = nm;
            nm = fmaxf(M, m4); Ssum = Ssum * __expf(M - nm) + s4 * __expf(m4 - nm); M = nm;
        }

        // Wave (64-lane) reduction.
        #pragma unroll
        for (int off = 32; off > 0; off >>= 1) {
            float om = __shfl_down(M, off);
            float os = __shfl_down(Ssum, off);
            float nm = fmaxf(M, om);
            Ssum = Ssum * __expf(M - nm) + os * __expf(om - nm);
            M = nm;
        }

        // Cross-wave reduction (5 waves).
        __shared__ float sm[THREADS / 64];
        __shared__ float ss[THREADS / 64];
        const int wave = threadIdx.x >> 6;
        const int lane = threadIdx.x & 63;
        if (lane == 0) { sm[wave] = M; ss[wave] = Ssum; }
        __syncthreads();

        if (threadIdx.x == 0) {
            float Mt = sm[0];
            float St = ss[0];
            #pragma unroll
            for (int w = 1; w < THREADS / 64; ++w) {
                float nm = fmaxf(Mt, sm[w]);
                St = St * __expf(Mt - nm) + ss[w] * __expf(sm[w] - nm);
                Mt = nm;
            }
            const float xt = rowp[tgt];               // L2-hot re-read, 64B
            const float nll = (Mt + __logf(St)) - xt; // -log_softmax[tgt] >= 0
            // Deterministic fixed-point accumulation: 2^-30 quantum.
            const long long ticks = llrintf(nll * 1073741824.0f);
            atomicAdd(&acc->sum_ticks, (unsigned long long)ticks);
            atomicAdd(&acc->count, 1u);
        }
    }

    // Completion counter: last block (of all NROWS) finalizes.
    if (threadIdx.x == 0) {
        __threadfence();  // release: our sum/count adds visible before done++
        unsigned int old = atomicAdd(&acc->done, 1u);
        if (old == NROWS - 1) {
            __threadfence();  // acquire
            unsigned long long st = atomicAdd(&acc->sum_ticks, 0ULL);
            unsigned int c = atomicAdd(&acc->count, 0u);
            double loss = ((double)(long long)st * (1.0 / 1073741824.0)) /
                          (double)(c > 0u ? c : 1u);
            out[0] = (float)loss;
        }
    }
}

extern "C" void kernel_launch(void* const* d_in, const int* in_sizes, int n_in,
                              void* d_out, int out_size, void* d_ws, size_t ws_size,
                              hipStream_t stream) {
    const float* logits  = (const float*)d_in[0];
    const int*   trg     = (const int*)d_in[1];
    const int*   lengths = (const int*)d_in[2];

    WsAcc* acc = (WsAcc*)d_ws;
    hipMemsetAsync(d_ws, 0, sizeof(WsAcc), stream);

    ce_fused_kernel<<<NROWS, THREADS, 0, stream>>>(logits, trg, lengths, acc,
                                                   (float*)d_out);
}

// Round 3
// 88.555 us; speedup vs baseline: 5.4629x; 5.4629x over previous
//
#include <hip/hip_runtime.h>
#include <math.h>

#define BB 16
#define SP1c 513
#define SS 512
#define VV 32000
#define NV4 (VV / 4)          // 8000 float4 per row
#define NROWS (BB * SS)       // 8192
#define THREADS 320           // 8000 / 320 = 25 iterations, exact fit
#define RTHREADS 256

#define UPD(M, S, v)                                                        \
    {                                                                       \
        float mx_ = fmaxf(fmaxf((v).x, (v).y), fmaxf((v).z, (v).w));        \
        float nm_ = fmaxf((M), mx_);                                        \
        (S) = (S) * __expf((M) - nm_) + __expf((v).x - nm_) +               \
              __expf((v).y - nm_) + __expf((v).z - nm_) +                   \
              __expf((v).w - nm_);                                          \
        (M) = nm_;                                                          \
    }

// One block per (b, s) row. Early-exit masked rows (~50%); 5 independent
// online-softmax accumulators break the exp-rescale dependency chain.
__global__ __launch_bounds__(THREADS) void ce_row_kernel(
    const float* __restrict__ logits,   // (B, SP1, V) f32
    const int* __restrict__ trg,        // (B, SP1)
    const int* __restrict__ lengths,    // (B,)
    float* __restrict__ row_loss,       // (NROWS,)
    int* __restrict__ row_valid)        // (NROWS,)
{
    const int row = blockIdx.x;
    const int b = row >> 9;
    const int s = row & 511;

    const int tgt = trg[b * SP1c + (s + 1)];
    const bool valid = (s < lengths[b]) && (tgt != 0);
    if (!valid) {
        if (threadIdx.x == 0) { row_loss[row] = 0.0f; row_valid[row] = 0; }
        return;
    }

    const float* rowp = logits + ((size_t)b * SP1c + (s + 1)) * VV;
    const float4* rp4 = reinterpret_cast<const float4*>(rowp);

    float m0 = -1e30f, m1 = -1e30f, m2 = -1e30f, m3 = -1e30f, m4 = -1e30f;
    float s0 = 0.f, s1 = 0.f, s2 = 0.f, s3 = 0.f, s4 = 0.f;

    int i = threadIdx.x;
    #pragma unroll
    for (int r = 0; r < 5; ++r) {
        float4 v0 = rp4[i];
        float4 v1 = rp4[i + THREADS];
        float4 v2 = rp4[i + 2 * THREADS];
        float4 v3 = rp4[i + 3 * THREADS];
        float4 v4 = rp4[i + 4 * THREADS];
        UPD(m0, s0, v0)
        UPD(m1, s1, v1)
        UPD(m2, s2, v2)
        UPD(m3, s3, v3)
        UPD(m4, s4, v4)
        i += 5 * THREADS;
    }

    // Merge 5 accumulators.
    float M = m0, Ssum = s0;
    {
        float nm = fmaxf(M, m1); Ssum = Ssum * __expf(M - nm) + s1 * __expf(m1 - nm); M = nm;
        nm = fmaxf(M, m2); Ssum = Ssum * __expf(M - nm) + s2 * __expf(m2 - nm); M = nm;
        nm = fmaxf(M, m3); Ssum = Ssum * __expf(M - nm) + s3 * __expf(m3 - nm); M = nm;
        nm = fmaxf(M, m4); Ssum = Ssum * __expf(M - nm) + s4 * __expf(m4 - nm); M = nm;
    }

    // Wave (64-lane) reduction.
    #pragma unroll
    for (int off = 32; off > 0; off >>= 1) {
        float om = __shfl_down(M, off);
        float os = __shfl_down(Ssum, off);
        float nm = fmaxf(M, om);
        Ssum = Ssum * __expf(M - nm) + os * __expf(om - nm);
        M = nm;
    }

    // Cross-wave reduction (5 waves).
    __shared__ float sm[THREADS / 64];
    __shared__ float ss[THREADS / 64];
    const int wave = threadIdx.x >> 6;
    const int lane = threadIdx.x & 63;
    if (lane == 0) { sm[wave] = M; ss[wave] = Ssum; }
    __syncthreads();

    if (threadIdx.x == 0) {
        float Mt = sm[0];
        float St = ss[0];
        #pragma unroll
        for (int w = 1; w < THREADS / 64; ++w) {
            float nm = fmaxf(Mt, sm[w]);
            St = St * __expf(Mt - nm) + ss[w] * __expf(sm[w] - nm);
            Mt = nm;
        }
        const float xt = rowp[tgt];
        row_loss[row] = (Mt + __logf(St)) - xt;   // -log_softmax[tgt]
        row_valid[row] = 1;
    }
}

// Deterministic final reduction: single block, fixed order, vectorized loads.
__global__ __launch_bounds__(RTHREADS) void ce_final_kernel(
    const float* __restrict__ row_loss,
    const int* __restrict__ row_valid,
    float* __restrict__ out)
{
    const float4* rl4 = reinterpret_cast<const float4*>(row_loss);
    const int4* rv4 = reinterpret_cast<const int4*>(row_valid);
    float s = 0.0f;
    int n = 0;
    for (int i = threadIdx.x; i < NROWS / 4; i += RTHREADS) {
        float4 v = rl4[i];
        int4 w = rv4[i];
        s += v.x + v.y + v.z + v.w;
        n += w.x + w.y + w.z + w.w;
    }
    #pragma unroll
    for (int off = 32; off > 0; off >>= 1) {
        s += __shfl_down(s, off);
        n += __shfl_down(n, off);
    }
    __shared__ float sl[RTHREADS / 64];
    __shared__ int sn[RTHREADS / 64];
    const int wave = threadIdx.x >> 6;
    const int lane = threadIdx.x & 63;
    if (lane == 0) { sl[wave] = s; sn[wave] = n; }
    __syncthreads();
    if (threadIdx.x == 0) {
        float ts = 0.0f;
        int tn = 0;
        #pragma unroll
        for (int w = 0; w < RTHREADS / 64; ++w) { ts += sl[w]; tn += sn[w]; }
        out[0] = ts / (float)(tn > 0 ? tn : 1);
    }
}

extern "C" void kernel_launch(void* const* d_in, const int* in_sizes, int n_in,
                              void* d_out, int out_size, void* d_ws, size_t ws_size,
                              hipStream_t stream) {
    const float* logits  = (const float*)d_in[0];
    const int*   trg     = (const int*)d_in[1];
    const int*   lengths = (const int*)d_in[2];

    float* row_loss  = (float*)d_ws;
    int*   row_valid = (int*)((char*)d_ws + NROWS * sizeof(float));

    ce_row_kernel<<<NROWS, THREADS, 0, stream>>>(logits, trg, lengths, row_loss, row_valid);
    ce_final_kernel<<<1, RTHREADS, 0, stream>>>(row_loss, row_valid, (float*)d_out);
}

// Round 4
// 75.960 us; speedup vs baseline: 6.3686x; 1.1658x over previous
//
#include <hip/hip_runtime.h>
#include <math.h>

#define BB 16
#define SP1c 513
#define SS 512
#define VV 32000
#define NV4 (VV / 4)          // 8000 float4 per row
#define NROWS (BB * SS)       // 8192
#define THREADS 320           // 8000 / 320 = 25 iterations, exact fit
#define RTHREADS 256

typedef float f32x4 __attribute__((ext_vector_type(4)));

static __device__ __forceinline__ f32x4 ntload4(const f32x4* p) {
    return __builtin_nontemporal_load(p);   // nt: bypass L2 pollution, zero reuse
}

#define UPD(M, S, v)                                                        \
    {                                                                       \
        float mx_ = fmaxf(fmaxf((v).x, (v).y), fmaxf((v).z, (v).w));        \
        float nm_ = fmaxf((M), mx_);                                        \
        (S) = (S) * __expf((M) - nm_) + __expf((v).x - nm_) +               \
              __expf((v).y - nm_) + __expf((v).z - nm_) +                   \
              __expf((v).w - nm_);                                          \
        (M) = nm_;                                                          \
    }

// One block per (b, s) row. Early-exit masked rows (~50%); 5 independent
// online-softmax accumulators break the exp-rescale dependency chain.
__global__ __launch_bounds__(THREADS) void ce_row_kernel(
    const float* __restrict__ logits,   // (B, SP1, V) f32
    const int* __restrict__ trg,        // (B, SP1)
    const int* __restrict__ lengths,    // (B,)
    float* __restrict__ row_loss,       // (NROWS,)
    int* __restrict__ row_valid)        // (NROWS,)
{
    const int row = blockIdx.x;
    const int b = row >> 9;
    const int s = row & 511;

    const int tgt = trg[b * SP1c + (s + 1)];
    const bool valid = (s < lengths[b]) && (tgt != 0);
    if (!valid) {
        if (threadIdx.x == 0) { row_loss[row] = 0.0f; row_valid[row] = 0; }
        return;
    }

    const float* rowp = logits + ((size_t)b * SP1c + (s + 1)) * VV;
    const f32x4* rp4 = reinterpret_cast<const f32x4*>(rowp);

    // Issue the target-logit load NOW (wave-uniform broadcast, 1 line);
    // its HBM latency hides under the 25-iteration stream below instead of
    // stalling the block tail after the reductions.
    const float xt = rowp[tgt];

    float m0 = -1e30f, m1 = -1e30f, m2 = -1e30f, m3 = -1e30f, m4 = -1e30f;
    float s0 = 0.f, s1 = 0.f, s2 = 0.f, s3 = 0.f, s4 = 0.f;

    int i = threadIdx.x;
    #pragma unroll
    for (int r = 0; r < 5; ++r) {
        f32x4 v0 = ntload4(&rp4[i]);
        f32x4 v1 = ntload4(&rp4[i + THREADS]);
        f32x4 v2 = ntload4(&rp4[i + 2 * THREADS]);
        f32x4 v3 = ntload4(&rp4[i + 3 * THREADS]);
        f32x4 v4 = ntload4(&rp4[i + 4 * THREADS]);
        UPD(m0, s0, v0)
        UPD(m1, s1, v1)
        UPD(m2, s2, v2)
        UPD(m3, s3, v3)
        UPD(m4, s4, v4)
        i += 5 * THREADS;
    }

    // Merge 5 accumulators.
    float M = m0, Ssum = s0;
    {
        float nm = fmaxf(M, m1); Ssum = Ssum * __expf(M - nm) + s1 * __expf(m1 - nm); M = nm;
        nm = fmaxf(M, m2); Ssum = Ssum * __expf(M - nm) + s2 * __expf(m2 - nm); M = nm;
        nm = fmaxf(M, m3); Ssum = Ssum * __expf(M - nm) + s3 * __expf(m3 - nm); M = nm;
        nm = fmaxf(M, m4); Ssum = Ssum * __expf(M - nm) + s4 * __expf(m4 - nm); M = nm;
    }

    // Wave (64-lane) reduction.
    #pragma unroll
    for (int off = 32; off > 0; off >>= 1) {
        float om = __shfl_down(M, off);
        float os = __shfl_down(Ssum, off);
        float nm = fmaxf(M, om);
        Ssum = Ssum * __expf(M - nm) + os * __expf(om - nm);
        M = nm;
    }

    // Cross-wave reduction (5 waves).
    __shared__ float sm[THREADS / 64];
    __shared__ float ss[THREADS / 64];
    const int wave = threadIdx.x >> 6;
    const int lane = threadIdx.x & 63;
    if (lane == 0) { sm[wave] = M; ss[wave] = Ssum; }
    __syncthreads();

    if (threadIdx.x == 0) {
        float Mt = sm[0];
        float St = ss[0];
        #pragma unroll
        for (int w = 1; w < THREADS / 64; ++w) {
            float nm = fmaxf(Mt, sm[w]);
            St = St * __expf(Mt - nm) + ss[w] * __expf(sm[w] - nm);
            Mt = nm;
        }
        row_loss[row] = (Mt + __logf(St)) - xt;   // -log_softmax[tgt]
        row_valid[row] = 1;
    }
}

// Deterministic final reduction: single block, fixed order, vectorized loads.
__global__ __launch_bounds__(RTHREADS) void ce_final_kernel(
    const float* __restrict__ row_loss,
    const int* __restrict__ row_valid,
    float* __restrict__ out)
{
    const f32x4* rl4 = reinterpret_cast<const f32x4*>(row_loss);
    const int4* rv4 = reinterpret_cast<const int4*>(row_valid);
    float s = 0.0f;
    int n = 0;
    for (int i = threadIdx.x; i < NROWS / 4; i += RTHREADS) {
        f32x4 v = rl4[i];
        int4 w = rv4[i];
        s += v.x + v.y + v.z + v.w;
        n += w.x + w.y + w.z + w.w;
    }
    #pragma unroll
    for (int off = 32; off > 0; off >>= 1) {
        s += __shfl_down(s, off);
        n += __shfl_down(n, off);
    }
    __shared__ float sl[RTHREADS / 64];
    __shared__ int sn[RTHREADS / 64];
    const int wave = threadIdx.x >> 6;
    const int lane = threadIdx.x & 63;
    if (lane == 0) { sl[wave] = s; sn[wave] = n; }
    __syncthreads();
    if (threadIdx.x == 0) {
        float ts = 0.0f;
        int tn = 0;
        #pragma unroll
        for (int w = 0; w < RTHREADS / 64; ++w) { ts += sl[w]; tn += sn[w]; }
        out[0] = ts / (float)(tn > 0 ? tn : 1);
    }
}

extern "C" void kernel_launch(void* const* d_in, const int* in_sizes, int n_in,
                              void* d_out, int out_size, void* d_ws, size_t ws_size,
                              hipStream_t stream) {
    const float* logits  = (const float*)d_in[0];
    const int*   trg     = (const int*)d_in[1];
    const int*   lengths = (const int*)d_in[2];

    float* row_loss  = (float*)d_ws;
    int*   row_valid = (int*)((char*)d_ws + NROWS * sizeof(float));

    ce_row_kernel<<<NROWS, THREADS, 0, stream>>>(logits, trg, lengths, row_loss, row_valid);
    ce_final_kernel<<<1, RTHREADS, 0, stream>>>(row_loss, row_valid, (float*)d_out);
}